// Round 11
// baseline (293.067 us; speedup 1.0000x reference)
//
#include <hip/hip_runtime.h>
#include <hip/hip_bf16.h>

// ---------------- problem constants ----------------
constexpr long NN = 20000;   // nodes
constexpr long NE = 160000;  // edges
constexpr long BB = 200;     // graphs
constexpr long TT = 8;       // taus
constexpr long GN = 100;     // nodes per graph

// ---------------- ws layout (f32 element offsets) ----------------
constexpr long O_FLAG = 0;                                      // int mode flag
constexpr long O_X    = 16;                 constexpr long N_X   = 40000;
constexpr long O_TAU  = O_X + N_X;          constexpr long N_TAU = 1600;
constexpr long O_W1   = O_TAU + N_TAU;      constexpr long N_W1  = 4096;
constexpr long O_Q1   = O_W1 + N_W1;        constexpr long N_Q   = 2048;
constexpr long O_K1   = O_Q1 + N_Q;
constexpr long O_B1   = O_K1 + N_Q;         constexpr long N_B   = 128;
constexpr long O_W2   = O_B1 + N_B;         constexpr long N_W2  = 262144;
constexpr long O_Q2   = O_W2 + N_W2;
constexpr long O_K2   = O_Q2 + N_Q;
constexpr long O_B2   = O_K2 + N_Q;
constexpr long O_CW   = O_B2 + N_B;         constexpr long N_CW  = 8192;
constexpr long O_CB   = O_CW + N_CW;
constexpr long O_F1W  = O_CB + N_B;         constexpr long N_FW  = 16384;
constexpr long O_F1B  = O_F1W + N_FW;
constexpr long O_F1SW = O_F1B + N_B;
constexpr long O_F1SB = O_F1SW + N_FW;
constexpr long O_F1EW = O_F1SB + N_B;
constexpr long O_F1EB = O_F1EW + N_FW;
constexpr long O_F2W  = O_F1EB + N_B;
constexpr long O_F2B  = O_F2W + N_FW;
constexpr long O_F2SW = O_F2B + N_B;
constexpr long O_F2SB = O_F2SW + N_FW;
constexpr long O_F2EW = O_F2SB + N_B;
constexpr long O_F2EB = O_F2EW + N_FW;
constexpr long O_AW   = O_F2EB + N_B;       constexpr long N_AW  = 1280;
constexpr long O_AB   = O_AW + N_AW;        constexpr long N_AB  = 16;  // 10 used
constexpr long O_ASW  = O_AB + N_AB;
constexpr long O_ASB  = O_ASW + N_AW;
constexpr long O_AEW  = O_ASB + N_AB;
constexpr long O_AEB  = O_AEW + N_AW;
constexpr long O_VW   = O_AEB + N_AB;       constexpr long N_VW  = 128;
constexpr long O_VB   = O_VW + N_VW;        constexpr long N_VB  = 16;  // 1 used
constexpr long O_VSW  = O_VB + N_VB;
constexpr long O_VSB  = O_VSW + N_VW;
constexpr long O_VEW  = O_VSB + N_VB;
constexpr long O_VEB  = O_VEW + N_VW;
// derived
constexpr long O_WQ1  = O_VEB + N_VB;       // [4][2][4] = 32  (r*8 + i*4 + h)
constexpr long O_WK1  = O_WQ1 + 32;
constexpr long O_WQ2  = O_WK1 + 32;         // [4][128][4] = 2048
constexpr long O_WK2  = O_WQ2 + 2048;
constexpr long O_CF1W = O_WK2 + 2048;       // combined noisy weights
constexpr long O_CF1B = O_CF1W + N_FW;
constexpr long O_CF2W = O_CF1B + N_B;
constexpr long O_CF2B = O_CF2W + N_FW;
constexpr long O_CAW  = O_CF2B + N_B;
constexpr long O_CAB  = O_CAW + N_AW;
constexpr long O_CVW  = O_CAB + N_AB;
constexpr long O_CVB  = O_CVW + N_VW;
constexpr long O_AL1  = O_CVB + N_VB;       // (spacer)
constexpr long O_AL2  = O_AL1 + NE*4;
constexpr long O_H1   = O_AL2 + NE*4;       // (spacer)
constexpr long O_H2   = O_H1 + NN*128;      // (spacer, h2 no longer stored)
constexpr long O_G    = O_H2 + NN*128;      // [200][128]
constexpr long O_Z0   = O_G + BB*128;
constexpr long O_Z1   = O_Z0 + BB*TT*128;
constexpr long O_Z2   = O_Z1 + BB*TT*128;
// CSR region
constexpr long O_AGG1 = O_Z2 + BB*TT*128;
constexpr long O_DEG  = O_AGG1;             // [NN] int
constexpr long O_CUR  = O_DEG + NN;         // [NN] int
constexpr long O_ROWP = O_CUR + NN;         // [NN+1] int (+pad)
constexpr long O_PERM = O_ROWP + NN + 8;    // [NE] int
// bf16 xw2 table [N][4][512] — inner 512 ordered d*4+h (viewed as u16)
constexpr long O_XW2  = O_AGG1 + NN*128 + NN*128 + NN*16;
constexpr long O_END_TABLE = O_XW2 + (NN*4*512)/2;
// MFMA-path extras
constexpr long MPAD   = 20096;
constexpr long O_H1B  = O_END_TABLE;                  // [20096][128] bf16
constexpr long O_W2BT = O_H1B + (MPAD*128)/2;         // [2048][128] bf16, row-permuted
constexpr long O_END2 = O_W2BT + (2048L*128)/2;
// AQ/AK tables: [N][16] f32, idx = r*4+h
constexpr long O_AQ   = O_END2;
constexpr long O_AK   = O_AQ + NN*16;
constexpr long O_END3 = O_AK + NN*16;
// transposed tail weights
constexpr long O_CWT   = O_END3;            // [64][128]
constexpr long O_CF1WT = O_CWT + 8192;      // [128][128] (in-major)
constexpr long O_CF2WT = O_CF1WT + 16384;
constexpr long O_END4  = O_CF2WT + 16384;

#define DEVFN __device__ __forceinline__

typedef __attribute__((ext_vector_type(8))) short bf16x8;
typedef __attribute__((ext_vector_type(4))) float f32x4;
typedef __attribute__((ext_vector_type(8))) unsigned short u16x8;

DEVFN float selu_f(float x){ return 1.0507009873554805f * (x > 0.f ? x : 1.6732632423543772f * expm1f(x)); }
DEVFN float lrelu_f(float x){ return x >= 0.f ? x : 0.2f * x; }
DEVFN float bf2f(unsigned short u){ return __uint_as_float(((unsigned)u) << 16); }
DEVFN unsigned short f2bfu(float x){
    __hip_bfloat16 b = __float2bfloat16(x);
    return *(unsigned short*)&b;
}
// 16-lane group reductions
DEVFN float g16_max(float v){
    #pragma unroll
    for (int off = 8; off > 0; off >>= 1) v = fmaxf(v, __shfl_xor(v, off));
    return v;
}
DEVFN float g16_sum(float v){
    #pragma unroll
    for (int off = 8; off > 0; off >>= 1) v += __shfl_xor(v, off);
    return v;
}
DEVFN float w64_sum(float v){
    #pragma unroll
    for (int off = 32; off > 0; off >>= 1) v += __shfl_xor(v, off);
    return v;
}

// ---------------- fused detect + histogram ----------------
__global__ void k_pre(const unsigned short* taus_u16, const int* ei, float* ws){
    if (blockIdx.x == 0){
        if (threadIdx.x == 0){
            int bf = 1;
            for (int i = 0; i < 128; i++) if (taus_u16[i] > 0x3F80u){ bf = 0; break; }
            ((int*)ws)[0] = bf;
        }
        return;
    }
    long e = (long)(blockIdx.x - 1)*blockDim.x + threadIdx.x;
    if (e >= NE) return;
    atomicAdd((int*)(ws + O_DEG) + ei[NE + e], 1);
}

__global__ void k_scan(float* ws){
    const int* deg = (const int*)(ws + O_DEG);
    int* rowp = (int*)(ws + O_ROWP);
    __shared__ int part[256];
    int tid = threadIdx.x;
    int base = tid * 79;
    int n = 0; if (base < NN) n = min(79, (int)NN - base);
    int s = 0;
    for (int i = 0; i < n; i++) s += deg[base + i];
    part[tid] = s;
    __syncthreads();
    if (tid == 0){
        int acc = 0;
        for (int i = 0; i < 256; i++){ int t = part[i]; part[i] = acc; acc += t; }
    }
    __syncthreads();
    int acc = part[tid];
    for (int i = 0; i < n; i++){ rowp[base + i] = acc; acc += deg[base + i]; }
    if (tid == 0) rowp[NN] = (int)NE;
}

// ---------------- fused convert (y<38) + CSR scatter (y=38) ----------------
struct ConvArgs { const void* src[38]; long off[38]; int n[38]; };

__global__ void k_conv_scatter(ConvArgs a, const int* ei, float* ws){
    int y = blockIdx.y;
    if (y == 38){
        long e = (long)blockIdx.x*blockDim.x + threadIdx.x;
        if (e >= NE) return;
        int dst = ei[NE + e];
        int pos = atomicAdd((int*)(ws + O_CUR) + dst, 1);
        ((int*)(ws + O_PERM))[((const int*)(ws + O_ROWP))[dst] + pos] = (int)e;
        return;
    }
    long off = a.off[y];
    if (off < 0) return;
    const void* s = a.src[y];
    int n = a.n[y];
    int bf = ((const int*)ws)[0];
    for (int i = blockIdx.x*blockDim.x + threadIdx.x; i < n; i += gridDim.x*blockDim.x){
        float v;
        if (bf){ unsigned short u = ((const unsigned short*)s)[i]; v = bf2f(u); }
        else   { v = ((const float*)s)[i]; }
        ws[off + i] = v;
    }
}

// ---------------- fused prep: fold(parallel) + noisy(+ff transpose) + w2b + zpad/cwT ------
__global__ void k_prep(float* ws){
    int phase = blockIdx.y;
    int idx = blockIdx.x*blockDim.x + threadIdx.x;
    if (phase == 0){
        // parallel fold: 16 lanes per output, outputs: 0..63 layer1, 64..4159 layer2
        int g = threadIdx.x >> 4, t = threadIdx.x & 15;
        int out = blockIdx.x*16 + g;
        if (out >= 4160) return;
        long wsrc, qsrc, dst; int h;
        if (out < 64){
            int tt = out & 31; h = tt & 3; int ri = tt >> 2;
            wsrc = O_W1 + (long)ri*512;
            qsrc = (out < 32) ? O_Q1 : O_K1;
            dst  = ((out < 32) ? O_WQ1 : O_WK1) + tt;
        } else {
            int tt = (out - 64) & 2047; h = tt & 3; int ri = tt >> 2;
            wsrc = O_W2 + (long)ri*512;
            qsrc = (out < 2112) ? O_Q2 : O_K2;
            dst  = ((out < 2112) ? O_WQ2 : O_WK2) + tt;
        }
        const float* W = ws + wsrc;
        const float* Q = ws + qsrc;
        float s = 0.f;
        #pragma unroll 8
        for (int i = 0; i < 32; i++){
            int o = t + i*16;
            s += W[o] * Q[o*4 + h];
        }
        s = g16_sum(s);
        if (t == 0) ws[dst] = s;
    } else if (phase == 1){
        const long tw[8] = {O_F1W,O_F2W,O_AW,O_VW, O_F1B,O_F2B,O_AB,O_VB};
        const long ts[8] = {O_F1SW,O_F2SW,O_ASW,O_VSW, O_F1SB,O_F2SB,O_ASB,O_VSB};
        const long te[8] = {O_F1EW,O_F2EW,O_AEW,O_VEW, O_F1EB,O_F2EB,O_AEB,O_VEB};
        const long td[8] = {O_CF1W,O_CF2W,O_CAW,O_CVW, O_CF1B,O_CF2B,O_CAB,O_CVB};
        const int  tn[8] = {16384,16384,1280,128, 128,128,10,1};
        const int  tb[8] = {0,16384,32768,34048, 34176,34304,34432,34442};
        int total = 34443;
        for (int i = idx; i < total; i += gridDim.x*blockDim.x){
            int t = 0;
            #pragma unroll
            for (int q = 1; q < 8; q++) if (i >= tb[q]) t = q;
            int j = i - tb[t];
            if (j < tn[t]){
                float v = ws[tw[t] + j] + ws[ts[t] + j]*ws[te[t] + j];
                ws[td[t] + j] = v;
                if (t == 0)      ws[O_CF1WT + (long)(j & 127)*128 + (j >> 7)] = v;
                else if (t == 1) ws[O_CF2WT + (long)(j & 127)*128 + (j >> 7)] = v;
            }
        }
    } else if (phase == 2){
        // W2 -> Bt row-permuted bf16: row n' = r*512 + d*4 + h holds W2[r][:,h*128+d]
        if (idx >= 262144) return;
        int np = idx & 2047, k = idx >> 11;
        int r = np >> 9, q = np & 511, d = q >> 2, h = q & 3;
        float v = ws[O_W2 + (long)r*65536 + (long)k*512 + h*128 + d];
        ((__hip_bfloat16*)(ws + O_W2BT))[(long)np*128 + k] = __float2bfloat16(v);
    } else {
        if (idx < 6144) ws[O_H1B + (20000L*128)/2 + idx] = 0.f;
        if (idx < 8192){
            int c = idx >> 7, d = idx & 127;
            ws[O_CWT + (long)c*128 + d] = ws[O_CW + (long)d*64 + c];
        }
    }
}

// ---------------- layer-1: 16 nodes/block, 16 lanes/node, barrier-free ----------------
__global__ __launch_bounds__(256) void k_node1(const int* ei, const int* et, float* ws){
    __shared__ float sacc[16][32];     // [group][r*8 + h*2 + i]
    int tid = threadIdx.x;
    int g = tid >> 4, t = tid & 15;
    long n = (long)blockIdx.x*16 + g;  // 1250*16 = 20000 exactly
    sacc[g][t] = 0.f; sacc[g][t + 16] = 0.f;
    const int* rowp = (const int*)(ws + O_ROWP);
    const int* perm = (const int*)(ws + O_PERM);
    int e0 = rowp[n], deg = rowp[n+1] - e0;
    float xd0 = ws[O_X + n*2], xd1 = ws[O_X + n*2 + 1];
    bool have = t < deg;
    float al[4], xs0 = 0.f, xs1 = 0.f; int rt0 = 0;
    float mx[4] = {-3.0e38f,-3.0e38f,-3.0e38f,-3.0e38f};
    if (have){
        int e = perm[e0 + t]; int src = ei[e]; rt0 = et[e];
        xs0 = ws[O_X + (long)src*2]; xs1 = ws[O_X + (long)src*2 + 1];
        const float* Wq = ws + O_WQ1 + rt0*8;
        const float* Wk = ws + O_WK1 + rt0*8;
        #pragma unroll
        for (int h = 0; h < 4; h++){
            al[h] = lrelu_f(xd0*Wq[h] + xd1*Wq[4+h] + xs0*Wk[h] + xs1*Wk[4+h]);
            mx[h] = al[h];
        }
    }
    for (int j0 = 16; j0 < deg; j0 += 16){   // rare (deg>16)
        int j = j0 + t;
        if (j < deg){
            int e = perm[e0 + j]; int src = ei[e]; int rt = et[e];
            float a0 = ws[O_X + (long)src*2], a1 = ws[O_X + (long)src*2 + 1];
            const float* Wq = ws + O_WQ1 + rt*8;
            const float* Wk = ws + O_WK1 + rt*8;
            #pragma unroll
            for (int h = 0; h < 4; h++)
                mx[h] = fmaxf(mx[h], lrelu_f(xd0*Wq[h] + xd1*Wq[4+h] + a0*Wk[h] + a1*Wk[4+h]));
        }
    }
    #pragma unroll
    for (int h = 0; h < 4; h++) mx[h] = g16_max(mx[h]);
    float den[4] = {0.f,0.f,0.f,0.f};
    if (have){
        #pragma unroll
        for (int h = 0; h < 4; h++){
            float ex = expf(al[h] - mx[h]);
            den[h] = ex;
            atomicAdd(&sacc[g][rt0*8 + h*2 + 0], ex*xs0);
            atomicAdd(&sacc[g][rt0*8 + h*2 + 1], ex*xs1);
        }
    }
    for (int j0 = 16; j0 < deg; j0 += 16){   // rare
        int j = j0 + t;
        if (j < deg){
            int e = perm[e0 + j]; int src = ei[e]; int rt = et[e];
            float a0 = ws[O_X + (long)src*2], a1 = ws[O_X + (long)src*2 + 1];
            const float* Wq = ws + O_WQ1 + rt*8;
            const float* Wk = ws + O_WK1 + rt*8;
            #pragma unroll
            for (int h = 0; h < 4; h++){
                float a = lrelu_f(xd0*Wq[h] + xd1*Wq[4+h] + a0*Wk[h] + a1*Wk[4+h]);
                float ex = expf(a - mx[h]);
                den[h] += ex;
                atomicAdd(&sacc[g][rt*8 + h*2 + 0], ex*a0);
                atomicAdd(&sacc[g][rt*8 + h*2 + 1], ex*a1);
            }
        }
    }
    #pragma unroll
    for (int h = 0; h < 4; h++) den[h] = g16_sum(den[h]);
    float rden[4];
    #pragma unroll
    for (int h = 0; h < 4; h++) rden[h] = den[h] > 0.f ? 0.25f/den[h] : 0.f;
    float v[8];
    #pragma unroll
    for (int k = 0; k < 8; k++) v[k] = 0.f;
    #pragma unroll
    for (int r = 0; r < 4; r++)
        #pragma unroll
        for (int h = 0; h < 4; h++){
            float t0 = sacc[g][r*8 + h*2 + 0]*rden[h];
            float t1 = sacc[g][r*8 + h*2 + 1]*rden[h];
            const float4* w0 = (const float4*)&ws[O_W1 + r*1024 +       h*128 + t*8];
            const float4* w1 = (const float4*)&ws[O_W1 + r*1024 + 512 + h*128 + t*8];
            float4 wa0 = w0[0], wa1 = w0[1], wb0 = w1[0], wb1 = w1[1];
            v[0] += wa0.x*t0 + wb0.x*t1;  v[1] += wa0.y*t0 + wb0.y*t1;
            v[2] += wa0.z*t0 + wb0.z*t1;  v[3] += wa0.w*t0 + wb0.w*t1;
            v[4] += wa1.x*t0 + wb1.x*t1;  v[5] += wa1.y*t0 + wb1.y*t1;
            v[6] += wa1.z*t0 + wb1.z*t1;  v[7] += wa1.w*t0 + wb1.w*t1;
        }
    float4 ba = *(const float4*)&ws[O_B1 + t*8];
    float4 bb = *(const float4*)&ws[O_B1 + t*8 + 4];
    u16x8 pk;
    pk[0] = f2bfu(selu_f(v[0] + ba.x)); pk[1] = f2bfu(selu_f(v[1] + ba.y));
    pk[2] = f2bfu(selu_f(v[2] + ba.z)); pk[3] = f2bfu(selu_f(v[3] + ba.w));
    pk[4] = f2bfu(selu_f(v[4] + bb.x)); pk[5] = f2bfu(selu_f(v[5] + bb.y));
    pk[6] = f2bfu(selu_f(v[6] + bb.z)); pk[7] = f2bfu(selu_f(v[7] + bb.w));
    *(u16x8*)((unsigned short*)(ws + O_H1B) + n*128 + t*8) = pk;
}

// ---------------- AQ/AK tables (from bf16 h1) ----------------
__global__ void k_aqk(float* ws){
    __shared__ float wq[128*16];
    __shared__ float wk[128*16];
    __shared__ float hl[16][129];
    int tid = threadIdx.x;
    long nb = (long)blockIdx.x * 16;
    const unsigned short* h1b = (const unsigned short*)(ws + O_H1B);
    #pragma unroll
    for (int c = 0; c < 8; c++){
        int idx = tid + c*256;
        int i = idx >> 4, o = idx & 15;
        int r = o >> 2, h = o & 3;
        wq[i*16 + o] = ws[O_WQ2 + r*512 + i*4 + h];
        wk[i*16 + o] = ws[O_WK2 + r*512 + i*4 + h];
        hl[idx >> 7][idx & 127] = bf2f(h1b[nb*128 + idx]);
    }
    __syncthreads();
    int j = tid >> 4, o = tid & 15;
    float aq = 0.f, ak = 0.f;
    #pragma unroll 4
    for (int i = 0; i < 128; i++){
        float hv = hl[j][i];
        aq += hv * wq[i*16 + o];
        ak += hv * wk[i*16 + o];
    }
    ws[O_AQ + (nb + j)*16 + o] = aq;
    ws[O_AK + (nb + j)*16 + o] = ak;
}

// ---------------- xw2 = h1 @ W2 via MFMA (B rows pre-permuted) ----------------
__global__ void k_xw2_mfma(float* ws){
    __shared__ __align__(16) unsigned short Ash[128*128];
    __shared__ __align__(16) unsigned short Bsh[128*128];
    const unsigned short* h1b  = (const unsigned short*)(ws + O_H1B);
    const unsigned short* w2bt = (const unsigned short*)(ws + O_W2BT);
    long bm = (long)blockIdx.x * 128;
    long bn = (long)blockIdx.y * 128;
    int tid = threadIdx.x;
    char* Ac = (char*)Ash; char* Bc = (char*)Bsh;
    #pragma unroll
    for (int i = 0; i < 8; i++){
        int c = tid + i*256;
        int row = c >> 4, kb = (c & 15) * 16;
        int off = row*256 + (kb ^ ((row & 7) << 4));
        *(bf16x8*)(Ac + off) = *(const bf16x8*)&h1b [(bm + row)*128 + (c & 15)*8];
        *(bf16x8*)(Bc + off) = *(const bf16x8*)&w2bt[(bn + row)*128 + (c & 15)*8];
    }
    __syncthreads();
    int w = tid >> 6, lane = tid & 63;
    int wm = (w >> 1) * 64, wn = (w & 1) * 64;
    int r16 = lane & 15, kq = lane >> 4;
    f32x4 acc[4][4] = {};
    #pragma unroll
    for (int ks = 0; ks < 4; ks++){
        int kbyte = ks*64 + kq*16;
        bf16x8 a[4], b[4];
        #pragma unroll
        for (int m = 0; m < 4; m++){
            int row = wm + m*16 + r16;
            a[m] = *(const bf16x8*)(Ac + row*256 + (kbyte ^ ((row & 7) << 4)));
        }
        #pragma unroll
        for (int n = 0; n < 4; n++){
            int row = wn + n*16 + r16;
            b[n] = *(const bf16x8*)(Bc + row*256 + (kbyte ^ ((row & 7) << 4)));
        }
        #pragma unroll
        for (int m = 0; m < 4; m++)
            #pragma unroll
            for (int n = 0; n < 4; n++)
                acc[m][n] = __builtin_amdgcn_mfma_f32_16x16x32_bf16(a[m], b[n], acc[m][n], 0, 0, 0);
    }
    __hip_bfloat16* xb = (__hip_bfloat16*)(ws + O_XW2);
    #pragma unroll
    for (int m = 0; m < 4; m++){
        long gr0 = bm + wm + m*16 + kq*4;
        #pragma unroll
        for (int j = 0; j < 4; j++){
            long gr = gr0 + j;
            if (gr < NN){
                #pragma unroll
                for (int n = 0; n < 4; n++){
                    long gc = bn + wn + n*16 + r16;
                    xb[gr*2048 + gc] = __float2bfloat16(acc[m][n][j]);
                }
            }
        }
    }
}

// ---------------- layer-2: 16 nodes/block, 16 lanes/node; fused graph-pool ----------------
__global__ __launch_bounds__(256) void k_node2(const int* ei, const int* et, float* ws){
    __shared__ float exs[16][16][4];   // normalized weights a_jh = ex*0.25/den
    __shared__ int   srts[16][16];
    int tid = threadIdx.x;
    int g = tid >> 4, t = tid & 15;
    long n = (long)blockIdx.x*16 + g;
    const int* rowp = (const int*)(ws + O_ROWP);
    const int* perm = (const int*)(ws + O_PERM);
    int e0 = rowp[n], deg = rowp[n+1] - e0;
    bool have = t < deg;
    float al[4]; int srt = 0;
    float mx[4] = {-3.0e38f,-3.0e38f,-3.0e38f,-3.0e38f};
    if (have){
        int e = perm[e0 + t]; int src = ei[e]; int rt = et[e]; srt = src*4 + rt;
        float4 q4 = *(const float4*)&ws[O_AQ + n*16 + rt*4];
        float4 k4 = *(const float4*)&ws[O_AK + (long)src*16 + rt*4];
        al[0] = lrelu_f(q4.x + k4.x); al[1] = lrelu_f(q4.y + k4.y);
        al[2] = lrelu_f(q4.z + k4.z); al[3] = lrelu_f(q4.w + k4.w);
        #pragma unroll
        for (int h = 0; h < 4; h++) mx[h] = al[h];
    }
    for (int j0 = 16; j0 < deg; j0 += 16){   // rare
        int j = j0 + t;
        if (j < deg){
            int e = perm[e0 + j]; int src = ei[e]; int rt = et[e];
            float4 q4 = *(const float4*)&ws[O_AQ + n*16 + rt*4];
            float4 k4 = *(const float4*)&ws[O_AK + (long)src*16 + rt*4];
            mx[0] = fmaxf(mx[0], lrelu_f(q4.x + k4.x));
            mx[1] = fmaxf(mx[1], lrelu_f(q4.y + k4.y));
            mx[2] = fmaxf(mx[2], lrelu_f(q4.z + k4.z));
            mx[3] = fmaxf(mx[3], lrelu_f(q4.w + k4.w));
        }
    }
    #pragma unroll
    for (int h = 0; h < 4; h++) mx[h] = g16_max(mx[h]);
    float den[4] = {0.f,0.f,0.f,0.f};
    float ex[4] = {0.f,0.f,0.f,0.f};
    if (have){
        #pragma unroll
        for (int h = 0; h < 4; h++){ ex[h] = expf(al[h] - mx[h]); den[h] = ex[h]; }
    }
    for (int j0 = 16; j0 < deg; j0 += 16){   // rare
        int j = j0 + t;
        if (j < deg){
            int e = perm[e0 + j]; int src = ei[e]; int rt = et[e];
            float4 q4 = *(const float4*)&ws[O_AQ + n*16 + rt*4];
            float4 k4 = *(const float4*)&ws[O_AK + (long)src*16 + rt*4];
            den[0] += expf(lrelu_f(q4.x + k4.x) - mx[0]);
            den[1] += expf(lrelu_f(q4.y + k4.y) - mx[1]);
            den[2] += expf(lrelu_f(q4.z + k4.z) - mx[2]);
            den[3] += expf(lrelu_f(q4.w + k4.w) - mx[3]);
        }
    }
    #pragma unroll
    for (int h = 0; h < 4; h++) den[h] = g16_sum(den[h]);
    float rd[4];
    #pragma unroll
    for (int h = 0; h < 4; h++) rd[h] = den[h] > 0.f ? 0.25f/den[h] : 0.f;
    if (have){
        exs[g][t][0] = ex[0]*rd[0]; exs[g][t][1] = ex[1]*rd[1];
        exs[g][t][2] = ex[2]*rd[2]; exs[g][t][3] = ex[3]*rd[3];
        srts[g][t] = srt;
    }
    // pass 3 (same-wave LDS read after write: ordered, no barrier)
    const unsigned short* xw2 = (const unsigned short*)(ws + O_XW2);
    float acc[8];
    #pragma unroll
    for (int k = 0; k < 8; k++) acc[k] = 0.f;
    int mdeg = min(deg, 16);
    for (int j = 0; j < mdeg; j++){
        float4 a4 = *(const float4*)exs[g][j];
        long sr = srts[g][j];
        const u16x8* row = (const u16x8*)(xw2 + sr*512 + t*32);
        u16x8 v0 = row[0], v1 = row[1], v2 = row[2], v3 = row[3];
        acc[0] += a4.x*bf2f(v0[0]) + a4.y*bf2f(v0[1]) + a4.z*bf2f(v0[2]) + a4.w*bf2f(v0[3]);
        acc[1] += a4.x*bf2f(v0[4]) + a4.y*bf2f(v0[5]) + a4.z*bf2f(v0[6]) + a4.w*bf2f(v0[7]);
        acc[2] += a4.x*bf2f(v1[0]) + a4.y*bf2f(v1[1]) + a4.z*bf2f(v1[2]) + a4.w*bf2f(v1[3]);
        acc[3] += a4.x*bf2f(v1[4]) + a4.y*bf2f(v1[5]) + a4.z*bf2f(v1[6]) + a4.w*bf2f(v1[7]);
        acc[4] += a4.x*bf2f(v2[0]) + a4.y*bf2f(v2[1]) + a4.z*bf2f(v2[2]) + a4.w*bf2f(v2[3]);
        acc[5] += a4.x*bf2f(v2[4]) + a4.y*bf2f(v2[5]) + a4.z*bf2f(v2[6]) + a4.w*bf2f(v2[7]);
        acc[6] += a4.x*bf2f(v3[0]) + a4.y*bf2f(v3[1]) + a4.z*bf2f(v3[2]) + a4.w*bf2f(v3[3]);
        acc[7] += a4.x*bf2f(v3[4]) + a4.y*bf2f(v3[5]) + a4.z*bf2f(v3[6]) + a4.w*bf2f(v3[7]);
    }
    for (int j = 16; j < deg; j++){          // rare: group-uniform recompute
        int e = perm[e0 + j]; int src = ei[e]; int rt = et[e];
        float4 q4 = *(const float4*)&ws[O_AQ + n*16 + rt*4];
        float4 k4 = *(const float4*)&ws[O_AK + (long)src*16 + rt*4];
        float4 a4;
        a4.x = expf(lrelu_f(q4.x + k4.x) - mx[0])*rd[0];
        a4.y = expf(lrelu_f(q4.y + k4.y) - mx[1])*rd[1];
        a4.z = expf(lrelu_f(q4.z + k4.z) - mx[2])*rd[2];
        a4.w = expf(lrelu_f(q4.w + k4.w) - mx[3])*rd[3];
        const u16x8* row = (const u16x8*)(xw2 + ((long)src*4 + rt)*512 + t*32);
        u16x8 v0 = row[0], v1 = row[1], v2 = row[2], v3 = row[3];
        acc[0] += a4.x*bf2f(v0[0]) + a4.y*bf2f(v0[1]) + a4.z*bf2f(v0[2]) + a4.w*bf2f(v0[3]);
        acc[1] += a4.x*bf2f(v0[4]) + a4.y*bf2f(v0[5]) + a4.z*bf2f(v0[6]) + a4.w*bf2f(v0[7]);
        acc[2] += a4.x*bf2f(v1[0]) + a4.y*bf2f(v1[1]) + a4.z*bf2f(v1[2]) + a4.w*bf2f(v1[3]);
        acc[3] += a4.x*bf2f(v1[4]) + a4.y*bf2f(v1[5]) + a4.z*bf2f(v1[6]) + a4.w*bf2f(v1[7]);
        acc[4] += a4.x*bf2f(v2[0]) + a4.y*bf2f(v2[1]) + a4.z*bf2f(v2[2]) + a4.w*bf2f(v2[3]);
        acc[5] += a4.x*bf2f(v2[4]) + a4.y*bf2f(v2[5]) + a4.z*bf2f(v2[6]) + a4.w*bf2f(v2[7]);
        acc[6] += a4.x*bf2f(v3[0]) + a4.y*bf2f(v3[1]) + a4.z*bf2f(v3[2]) + a4.w*bf2f(v3[3]);
        acc[7] += a4.x*bf2f(v3[4]) + a4.y*bf2f(v3[5]) + a4.z*bf2f(v3[6]) + a4.w*bf2f(v3[7]);
    }
    float4 ba = *(const float4*)&ws[O_B2 + t*8];
    float4 bb = *(const float4*)&ws[O_B2 + t*8 + 4];
    // fused global_add_pool: h2 row goes straight into graph accumulator G[b]
    int b = (int)(n / GN);
    float* Gp = ws + O_G + (long)b*128 + t*8;
    atomicAdd(&Gp[0], selu_f(acc[0] + ba.x));
    atomicAdd(&Gp[1], selu_f(acc[1] + ba.y));
    atomicAdd(&Gp[2], selu_f(acc[2] + ba.z));
    atomicAdd(&Gp[3], selu_f(acc[3] + ba.w));
    atomicAdd(&Gp[4], selu_f(acc[4] + bb.x));
    atomicAdd(&Gp[5], selu_f(acc[5] + bb.y));
    atomicAdd(&Gp[6], selu_f(acc[6] + bb.z));
    atomicAdd(&Gp[7], selu_f(acc[7] + bb.w));
}

// ---------------- fused tail with transposed (coalesced) weights ----------------
__global__ void k_tail(float* ws, void* d_out, const void* taus_raw){
    __shared__ float cs[64];
    __shared__ float row0[128], row1[128];
    __shared__ float red[2][12];
    __shared__ float advs[12];
    int bt = blockIdx.x, t = threadIdx.x;
    int b = bt >> 3;
    int wid = t >> 6;
    if (t < 64){
        float tau = ws[O_TAU + bt];
        cs[t] = cosf(tau * (3.14159265358979323846f * (float)(t + 1)));
    }
    __syncthreads();
    {
        const float* cwt = ws + O_CWT;                // [c][t]
        float s = ws[O_CB + t];
        #pragma unroll 8
        for (int c = 0; c < 64; c++) s += cs[c]*cwt[c*128 + t];
        s = fmaxf(s, 0.f);
        row0[t] = ws[O_G + (long)b*128 + t] * s;
    }
    __syncthreads();
    {
        const float* wt = ws + O_CF1WT;               // [i][t]
        float s = ws[O_CF1B + t];
        #pragma unroll 8
        for (int i = 0; i < 128; i++) s += row0[i]*wt[i*128 + t];
        row1[t] = selu_f(s);
    }
    __syncthreads();
    float r2;
    {
        const float* wt = ws + O_CF2WT;               // [i][t]
        float s = ws[O_CF2B + t];
        #pragma unroll 8
        for (int i = 0; i < 128; i++) s += row1[i]*wt[i*128 + t];
        r2 = selu_f(s);
    }
    // head: all threads compute coalesced partials, wave-reduce
    float part[11];
    #pragma unroll
    for (int a = 0; a < 10; a++) part[a] = r2 * ws[O_CAW + (long)a*128 + t];
    part[10] = r2 * ws[O_CVW + t];
    #pragma unroll
    for (int a = 0; a < 11; a++) part[a] = w64_sum(part[a]);
    if ((t & 63) == 0){
        #pragma unroll
        for (int a = 0; a < 11; a++) red[wid][a] = part[a];
    }
    __syncthreads();
    if (t == 0){
        float m = 0.f;
        #pragma unroll
        for (int a = 0; a < 11; a++) advs[a] = red[0][a] + red[1][a];
        #pragma unroll
        for (int a = 0; a < 10; a++) m += advs[a];
        m *= 0.1f;
        float val = advs[10];
        int bf = ((const int*)ws)[0];
        if (bf){
            __hip_bfloat16* out = (__hip_bfloat16*)d_out;
            for (int a = 0; a < 10; a++) out[(long)bt*10 + a] = __float2bfloat16(val + advs[a] - m);
            ((unsigned short*)d_out)[16000 + bt] = ((const unsigned short*)taus_raw)[bt];
        } else {
            float* out = (float*)d_out;
            for (int a = 0; a < 10; a++) out[(long)bt*10 + a] = val + advs[a] - m;
            out[16000 + bt] = ((const float*)taus_raw)[bt];
        }
    }
}

// ---------------- launch ----------------
extern "C" void kernel_launch(void* const* d_in, const int* in_sizes, int n_in,
                              void* d_out, int out_size, void* d_ws, size_t ws_size,
                              hipStream_t stream){
    (void)in_sizes; (void)n_in; (void)out_size; (void)ws_size;
    float* ws = (float*)d_ws;
    const int* ei = (const int*)d_in[1];
    const int* et = (const int*)d_in[2];

    hipMemsetAsync(ws + O_DEG, 0, (size_t)(2*NN)*4, stream);
    hipMemsetAsync(ws + O_G,   0, (size_t)(BB*128)*4, stream);

    k_pre<<<626, 256, 0, stream>>>((const unsigned short*)d_in[3], ei, ws);
    k_scan<<<1, 256, 0, stream>>>(ws);

    ConvArgs ca;
    static const long conv_o[38] = {
        O_X, -1, -1, O_TAU, O_W1, O_Q1, O_K1, O_B1, O_W2, O_Q2, O_K2, O_B2, O_CW, O_CB,
        O_F1W, O_F1B, O_F1SW, O_F1SB, O_F1EW, O_F1EB,
        O_F2W, O_F2B, O_F2SW, O_F2SB, O_F2EW, O_F2EB,
        O_AW, O_AB, O_ASW, O_ASB, O_AEW, O_AEB,
        O_VW, O_VB, O_VSW, O_VSB, O_VEW, O_VEB };
    static const int conv_n[38] = {
        40000, 0, 0, 1600, 4096, 2048, 2048, 128, 262144, 2048, 2048, 128, 8192, 128,
        16384, 128, 16384, 128, 16384, 128,
        16384, 128, 16384, 128, 16384, 128,
        1280, 10, 1280, 10, 1280, 10,
        128, 1, 128, 1, 128, 1 };
    for (int i = 0; i < 38; i++){ ca.src[i] = d_in[i]; ca.off[i] = conv_o[i]; ca.n[i] = conv_n[i]; }
    k_conv_scatter<<<dim3(625, 39), 256, 0, stream>>>(ca, ei, ws);

    k_prep<<<dim3(1024, 4), 256, 0, stream>>>(ws);

    k_node1<<<1250, 256, 0, stream>>>(ei, et, ws);

    k_xw2_mfma<<<dim3(157, 16), 256, 0, stream>>>(ws);
    k_aqk<<<1250, 256, 0, stream>>>(ws);
    k_node2<<<1250, 256, 0, stream>>>(ei, et, ws);

    k_tail<<<1600, 128, 0, stream>>>(ws, d_out, d_in[3]);
}

// Round 13
// 214.297 us; speedup vs baseline: 1.3676x; 1.3676x over previous
//
#include <hip/hip_runtime.h>
#include <hip/hip_bf16.h>

// ---------------- problem constants ----------------
constexpr long NN = 20000;   // nodes
constexpr long NE = 160000;  // edges
constexpr long BB = 200;     // graphs
constexpr long TT = 8;       // taus
constexpr long GN = 100;     // nodes per graph

// ---------------- ws layout (f32 element offsets) ----------------
constexpr long O_FLAG = 0;                                      // int mode flag
constexpr long O_X    = 16;                 constexpr long N_X   = 40000;
constexpr long O_TAU  = O_X + N_X;          constexpr long N_TAU = 1600;
constexpr long O_W1   = O_TAU + N_TAU;      constexpr long N_W1  = 4096;
constexpr long O_Q1   = O_W1 + N_W1;        constexpr long N_Q   = 2048;
constexpr long O_K1   = O_Q1 + N_Q;
constexpr long O_B1   = O_K1 + N_Q;         constexpr long N_B   = 128;
constexpr long O_W2   = O_B1 + N_B;         constexpr long N_W2  = 262144;
constexpr long O_Q2   = O_W2 + N_W2;
constexpr long O_K2   = O_Q2 + N_Q;
constexpr long O_B2   = O_K2 + N_Q;
constexpr long O_CW   = O_B2 + N_B;         constexpr long N_CW  = 8192;
constexpr long O_CB   = O_CW + N_CW;
constexpr long O_F1W  = O_CB + N_B;         constexpr long N_FW  = 16384;
constexpr long O_F1B  = O_F1W + N_FW;
constexpr long O_F1SW = O_F1B + N_B;
constexpr long O_F1SB = O_F1SW + N_FW;
constexpr long O_F1EW = O_F1SB + N_B;
constexpr long O_F1EB = O_F1EW + N_FW;
constexpr long O_F2W  = O_F1EB + N_B;
constexpr long O_F2B  = O_F2W + N_FW;
constexpr long O_F2SW = O_F2B + N_B;
constexpr long O_F2SB = O_F2SW + N_FW;
constexpr long O_F2EW = O_F2SB + N_B;
constexpr long O_F2EB = O_F2EW + N_FW;
constexpr long O_AW   = O_F2EB + N_B;       constexpr long N_AW  = 1280;
constexpr long O_AB   = O_AW + N_AW;        constexpr long N_AB  = 16;  // 10 used
constexpr long O_ASW  = O_AB + N_AB;
constexpr long O_ASB  = O_ASW + N_AW;
constexpr long O_AEW  = O_ASB + N_AB;
constexpr long O_AEB  = O_AEW + N_AW;
constexpr long O_VW   = O_AEB + N_AB;       constexpr long N_VW  = 128;
constexpr long O_VB   = O_VW + N_VW;        constexpr long N_VB  = 16;  // 1 used
constexpr long O_VSW  = O_VB + N_VB;
constexpr long O_VSB  = O_VSW + N_VW;
constexpr long O_VEW  = O_VSB + N_VB;
constexpr long O_VEB  = O_VEW + N_VW;
// derived
constexpr long O_WQ1  = O_VEB + N_VB;       // [4][2][4] = 32  (r*8 + i*4 + h)
constexpr long O_WK1  = O_WQ1 + 32;
constexpr long O_WQ2  = O_WK1 + 32;         // [4][128][4] = 2048
constexpr long O_WK2  = O_WQ2 + 2048;
constexpr long O_CF1W = O_WK2 + 2048;       // combined noisy weights
constexpr long O_CF1B = O_CF1W + N_FW;
constexpr long O_CF2W = O_CF1B + N_B;
constexpr long O_CF2B = O_CF2W + N_FW;
constexpr long O_CAW  = O_CF2B + N_B;
constexpr long O_CAB  = O_CAW + N_AW;
constexpr long O_CVW  = O_CAB + N_AB;
constexpr long O_CVB  = O_CVW + N_VW;
constexpr long O_AL1  = O_CVB + N_VB;       // (spacer)
constexpr long O_AL2  = O_AL1 + NE*4;
constexpr long O_H1   = O_AL2 + NE*4;       // (spacer)
constexpr long O_H2   = O_H1 + NN*128;      // [N][128] f32
constexpr long O_G    = O_H2 + NN*128;      // [200][128]
constexpr long O_Z0   = O_G + BB*128;
constexpr long O_Z1   = O_Z0 + BB*TT*128;
constexpr long O_Z2   = O_Z1 + BB*TT*128;
// CSR region
constexpr long O_AGG1 = O_Z2 + BB*TT*128;
constexpr long O_DEG  = O_AGG1;             // [NN] int
constexpr long O_CUR  = O_DEG + NN;         // [NN] int
constexpr long O_ROWP = O_CUR + NN;         // [NN+1] int (+pad)
constexpr long O_PERM = O_ROWP + NN + 8;    // [NE] int
// bf16 xw2 table [N][4][512] — inner 512 ordered d*4+h (viewed as u16)
constexpr long O_XW2  = O_AGG1 + NN*128 + NN*128 + NN*16;
constexpr long O_END_TABLE = O_XW2 + (NN*4*512)/2;
// MFMA-path extras
constexpr long MPAD   = 20096;
constexpr long O_H1B  = O_END_TABLE;                  // [20096][128] bf16
constexpr long O_W2BT = O_H1B + (MPAD*128)/2;         // [2048][128] bf16, row-permuted
constexpr long O_END2 = O_W2BT + (2048L*128)/2;
// AQ/AK tables: [N][16] f32, idx = r*4+h
constexpr long O_AQ   = O_END2;
constexpr long O_AK   = O_AQ + NN*16;
constexpr long O_END3 = O_AK + NN*16;
// transposed tail weights
constexpr long O_CWT   = O_END3;            // [64][128]
constexpr long O_CF1WT = O_CWT + 8192;      // [128][128] (in-major)
constexpr long O_CF2WT = O_CF1WT + 16384;
constexpr long O_END4  = O_CF2WT + 16384;

#define DEVFN __device__ __forceinline__

typedef __attribute__((ext_vector_type(8))) short bf16x8;
typedef __attribute__((ext_vector_type(4))) float f32x4;
typedef __attribute__((ext_vector_type(8))) unsigned short u16x8;

DEVFN float selu_f(float x){ return 1.0507009873554805f * (x > 0.f ? x : 1.6732632423543772f * expm1f(x)); }
DEVFN float lrelu_f(float x){ return x >= 0.f ? x : 0.2f * x; }
DEVFN float bf2f(unsigned short u){ return __uint_as_float(((unsigned)u) << 16); }
DEVFN unsigned short f2bfu(float x){
    __hip_bfloat16 b = __float2bfloat16(x);
    return *(unsigned short*)&b;
}
// 16-lane group reductions
DEVFN float g16_max(float v){
    #pragma unroll
    for (int off = 8; off > 0; off >>= 1) v = fmaxf(v, __shfl_xor(v, off));
    return v;
}
DEVFN float g16_sum(float v){
    #pragma unroll
    for (int off = 8; off > 0; off >>= 1) v += __shfl_xor(v, off);
    return v;
}
DEVFN float w64_sum(float v){
    #pragma unroll
    for (int off = 32; off > 0; off >>= 1) v += __shfl_xor(v, off);
    return v;
}

// ---------------- fused detect + histogram ----------------
__global__ void k_pre(const unsigned short* taus_u16, const int* ei, float* ws){
    if (blockIdx.x == 0){
        if (threadIdx.x == 0){
            int bf = 1;
            for (int i = 0; i < 128; i++) if (taus_u16[i] > 0x3F80u){ bf = 0; break; }
            ((int*)ws)[0] = bf;
        }
        return;
    }
    long e = (long)(blockIdx.x - 1)*blockDim.x + threadIdx.x;
    if (e >= NE) return;
    atomicAdd((int*)(ws + O_DEG) + ei[NE + e], 1);
}

__global__ void k_scan(float* ws){
    const int* deg = (const int*)(ws + O_DEG);
    int* rowp = (int*)(ws + O_ROWP);
    __shared__ int part[256];
    int tid = threadIdx.x;
    int base = tid * 79;
    int n = 0; if (base < NN) n = min(79, (int)NN - base);
    int s = 0;
    for (int i = 0; i < n; i++) s += deg[base + i];
    part[tid] = s;
    __syncthreads();
    if (tid == 0){
        int acc = 0;
        for (int i = 0; i < 256; i++){ int t = part[i]; part[i] = acc; acc += t; }
    }
    __syncthreads();
    int acc = part[tid];
    for (int i = 0; i < n; i++){ rowp[base + i] = acc; acc += deg[base + i]; }
    if (tid == 0) rowp[NN] = (int)NE;
}

// ---------------- fused convert (y<38) + CSR scatter (y=38) ----------------
struct ConvArgs { const void* src[38]; long off[38]; int n[38]; };

__global__ void k_conv_scatter(ConvArgs a, const int* ei, float* ws){
    int y = blockIdx.y;
    if (y == 38){
        long e = (long)blockIdx.x*blockDim.x + threadIdx.x;
        if (e >= NE) return;
        int dst = ei[NE + e];
        int pos = atomicAdd((int*)(ws + O_CUR) + dst, 1);
        ((int*)(ws + O_PERM))[((const int*)(ws + O_ROWP))[dst] + pos] = (int)e;
        return;
    }
    long off = a.off[y];
    if (off < 0) return;
    const void* s = a.src[y];
    int n = a.n[y];
    int bf = ((const int*)ws)[0];
    for (int i = blockIdx.x*blockDim.x + threadIdx.x; i < n; i += gridDim.x*blockDim.x){
        float v;
        if (bf){ unsigned short u = ((const unsigned short*)s)[i]; v = bf2f(u); }
        else   { v = ((const float*)s)[i]; }
        ws[off + i] = v;
    }
}

// ---------------- fused prep: fold(parallel) + noisy(+ff transpose) + w2b + zpad/cwT ------
// NOTE: must be launched with >= 1024 blocks in x (phase 2 covers 262144 via direct index).
__global__ void k_prep(float* ws){
    int phase = blockIdx.y;
    int idx = blockIdx.x*blockDim.x + threadIdx.x;
    if (phase == 0){
        // parallel fold: 16 lanes per output, outputs: 0..63 layer1, 64..4159 layer2
        int g = threadIdx.x >> 4, t = threadIdx.x & 15;
        int out = blockIdx.x*16 + g;
        if (out >= 4160) return;
        long wsrc, qsrc, dst; int h;
        if (out < 64){
            int tt = out & 31; h = tt & 3; int ri = tt >> 2;
            wsrc = O_W1 + (long)ri*512;
            qsrc = (out < 32) ? O_Q1 : O_K1;
            dst  = ((out < 32) ? O_WQ1 : O_WK1) + tt;
        } else {
            int tt = (out - 64) & 2047; h = tt & 3; int ri = tt >> 2;
            wsrc = O_W2 + (long)ri*512;
            qsrc = (out < 2112) ? O_Q2 : O_K2;
            dst  = ((out < 2112) ? O_WQ2 : O_WK2) + tt;
        }
        const float* W = ws + wsrc;
        const float* Q = ws + qsrc;
        float s = 0.f;
        #pragma unroll 8
        for (int i = 0; i < 32; i++){
            int o = t + i*16;
            s += W[o] * Q[o*4 + h];
        }
        s = g16_sum(s);
        if (t == 0) ws[dst] = s;
    } else if (phase == 1){
        const long tw[8] = {O_F1W,O_F2W,O_AW,O_VW, O_F1B,O_F2B,O_AB,O_VB};
        const long ts[8] = {O_F1SW,O_F2SW,O_ASW,O_VSW, O_F1SB,O_F2SB,O_ASB,O_VSB};
        const long te[8] = {O_F1EW,O_F2EW,O_AEW,O_VEW, O_F1EB,O_F2EB,O_AEB,O_VEB};
        const long td[8] = {O_CF1W,O_CF2W,O_CAW,O_CVW, O_CF1B,O_CF2B,O_CAB,O_CVB};
        const int  tn[8] = {16384,16384,1280,128, 128,128,10,1};
        const int  tb[8] = {0,16384,32768,34048, 34176,34304,34432,34442};
        int total = 34443;
        for (int i = idx; i < total; i += gridDim.x*blockDim.x){
            int t = 0;
            #pragma unroll
            for (int q = 1; q < 8; q++) if (i >= tb[q]) t = q;
            int j = i - tb[t];
            if (j < tn[t]){
                float v = ws[tw[t] + j] + ws[ts[t] + j]*ws[te[t] + j];
                ws[td[t] + j] = v;
                if (t == 0)      ws[O_CF1WT + (long)(j & 127)*128 + (j >> 7)] = v;
                else if (t == 1) ws[O_CF2WT + (long)(j & 127)*128 + (j >> 7)] = v;
            }
        }
    } else if (phase == 2){
        // W2 -> Bt row-permuted bf16: row n' = r*512 + d*4 + h holds W2[r][:,h*128+d]
        if (idx >= 262144) return;
        int np = idx & 2047, k = idx >> 11;
        int r = np >> 9, q = np & 511, d = q >> 2, h = q & 3;
        float v = ws[O_W2 + (long)r*65536 + (long)k*512 + h*128 + d];
        ((__hip_bfloat16*)(ws + O_W2BT))[(long)np*128 + k] = __float2bfloat16(v);
    } else {
        if (idx < 6144) ws[O_H1B + (20000L*128)/2 + idx] = 0.f;
        if (idx < 8192){
            int c = idx >> 7, d = idx & 127;
            ws[O_CWT + (long)c*128 + d] = ws[O_CW + (long)d*64 + c];
        }
    }
}

// ---------------- layer-1: 16 nodes/block, 16 lanes/node, barrier-free ----------------
__global__ __launch_bounds__(256) void k_node1(const int* ei, const int* et, float* ws){
    __shared__ float sacc[16][32];     // [group][r*8 + h*2 + i]
    int tid = threadIdx.x;
    int g = tid >> 4, t = tid & 15;
    long n = (long)blockIdx.x*16 + g;  // 1250*16 = 20000 exactly
    sacc[g][t] = 0.f; sacc[g][t + 16] = 0.f;
    const int* rowp = (const int*)(ws + O_ROWP);
    const int* perm = (const int*)(ws + O_PERM);
    int e0 = rowp[n], deg = rowp[n+1] - e0;
    float xd0 = ws[O_X + n*2], xd1 = ws[O_X + n*2 + 1];
    bool have = t < deg;
    float al[4], xs0 = 0.f, xs1 = 0.f; int rt0 = 0;
    float mx[4] = {-3.0e38f,-3.0e38f,-3.0e38f,-3.0e38f};
    if (have){
        int e = perm[e0 + t]; int src = ei[e]; rt0 = et[e];
        xs0 = ws[O_X + (long)src*2]; xs1 = ws[O_X + (long)src*2 + 1];
        const float* Wq = ws + O_WQ1 + rt0*8;
        const float* Wk = ws + O_WK1 + rt0*8;
        #pragma unroll
        for (int h = 0; h < 4; h++){
            al[h] = lrelu_f(xd0*Wq[h] + xd1*Wq[4+h] + xs0*Wk[h] + xs1*Wk[4+h]);
            mx[h] = al[h];
        }
    }
    for (int j0 = 16; j0 < deg; j0 += 16){   // rare (deg>16)
        int j = j0 + t;
        if (j < deg){
            int e = perm[e0 + j]; int src = ei[e]; int rt = et[e];
            float a0 = ws[O_X + (long)src*2], a1 = ws[O_X + (long)src*2 + 1];
            const float* Wq = ws + O_WQ1 + rt*8;
            const float* Wk = ws + O_WK1 + rt*8;
            #pragma unroll
            for (int h = 0; h < 4; h++)
                mx[h] = fmaxf(mx[h], lrelu_f(xd0*Wq[h] + xd1*Wq[4+h] + a0*Wk[h] + a1*Wk[4+h]));
        }
    }
    #pragma unroll
    for (int h = 0; h < 4; h++) mx[h] = g16_max(mx[h]);
    float den[4] = {0.f,0.f,0.f,0.f};
    if (have){
        #pragma unroll
        for (int h = 0; h < 4; h++){
            float ex = expf(al[h] - mx[h]);
            den[h] = ex;
            atomicAdd(&sacc[g][rt0*8 + h*2 + 0], ex*xs0);
            atomicAdd(&sacc[g][rt0*8 + h*2 + 1], ex*xs1);
        }
    }
    for (int j0 = 16; j0 < deg; j0 += 16){   // rare
        int j = j0 + t;
        if (j < deg){
            int e = perm[e0 + j]; int src = ei[e]; int rt = et[e];
            float a0 = ws[O_X + (long)src*2], a1 = ws[O_X + (long)src*2 + 1];
            const float* Wq = ws + O_WQ1 + rt*8;
            const float* Wk = ws + O_WK1 + rt*8;
            #pragma unroll
            for (int h = 0; h < 4; h++){
                float a = lrelu_f(xd0*Wq[h] + xd1*Wq[4+h] + a0*Wk[h] + a1*Wk[4+h]);
                float ex = expf(a - mx[h]);
                den[h] += ex;
                atomicAdd(&sacc[g][rt*8 + h*2 + 0], ex*a0);
                atomicAdd(&sacc[g][rt*8 + h*2 + 1], ex*a1);
            }
        }
    }
    #pragma unroll
    for (int h = 0; h < 4; h++) den[h] = g16_sum(den[h]);
    float rden[4];
    #pragma unroll
    for (int h = 0; h < 4; h++) rden[h] = den[h] > 0.f ? 0.25f/den[h] : 0.f;
    float v[8];
    #pragma unroll
    for (int k = 0; k < 8; k++) v[k] = 0.f;
    #pragma unroll
    for (int r = 0; r < 4; r++)
        #pragma unroll
        for (int h = 0; h < 4; h++){
            float t0 = sacc[g][r*8 + h*2 + 0]*rden[h];
            float t1 = sacc[g][r*8 + h*2 + 1]*rden[h];
            const float4* w0 = (const float4*)&ws[O_W1 + r*1024 +       h*128 + t*8];
            const float4* w1 = (const float4*)&ws[O_W1 + r*1024 + 512 + h*128 + t*8];
            float4 wa0 = w0[0], wa1 = w0[1], wb0 = w1[0], wb1 = w1[1];
            v[0] += wa0.x*t0 + wb0.x*t1;  v[1] += wa0.y*t0 + wb0.y*t1;
            v[2] += wa0.z*t0 + wb0.z*t1;  v[3] += wa0.w*t0 + wb0.w*t1;
            v[4] += wa1.x*t0 + wb1.x*t1;  v[5] += wa1.y*t0 + wb1.y*t1;
            v[6] += wa1.z*t0 + wb1.z*t1;  v[7] += wa1.w*t0 + wb1.w*t1;
        }
    float4 ba = *(const float4*)&ws[O_B1 + t*8];
    float4 bb = *(const float4*)&ws[O_B1 + t*8 + 4];
    u16x8 pk;
    pk[0] = f2bfu(selu_f(v[0] + ba.x)); pk[1] = f2bfu(selu_f(v[1] + ba.y));
    pk[2] = f2bfu(selu_f(v[2] + ba.z)); pk[3] = f2bfu(selu_f(v[3] + ba.w));
    pk[4] = f2bfu(selu_f(v[4] + bb.x)); pk[5] = f2bfu(selu_f(v[5] + bb.y));
    pk[6] = f2bfu(selu_f(v[6] + bb.z)); pk[7] = f2bfu(selu_f(v[7] + bb.w));
    *(u16x8*)((unsigned short*)(ws + O_H1B) + n*128 + t*8) = pk;
}

// ---------------- AQ/AK tables (from bf16 h1) ----------------
__global__ void k_aqk(float* ws){
    __shared__ float wq[128*16];
    __shared__ float wk[128*16];
    __shared__ float hl[16][129];
    int tid = threadIdx.x;
    long nb = (long)blockIdx.x * 16;
    const unsigned short* h1b = (const unsigned short*)(ws + O_H1B);
    #pragma unroll
    for (int c = 0; c < 8; c++){
        int idx = tid + c*256;
        int i = idx >> 4, o = idx & 15;
        int r = o >> 2, h = o & 3;
        wq[i*16 + o] = ws[O_WQ2 + r*512 + i*4 + h];
        wk[i*16 + o] = ws[O_WK2 + r*512 + i*4 + h];
        hl[idx >> 7][idx & 127] = bf2f(h1b[nb*128 + idx]);
    }
    __syncthreads();
    int j = tid >> 4, o = tid & 15;
    float aq = 0.f, ak = 0.f;
    #pragma unroll 4
    for (int i = 0; i < 128; i++){
        float hv = hl[j][i];
        aq += hv * wq[i*16 + o];
        ak += hv * wk[i*16 + o];
    }
    ws[O_AQ + (nb + j)*16 + o] = aq;
    ws[O_AK + (nb + j)*16 + o] = ak;
}

// ---------------- xw2 = h1 @ W2 via MFMA (B rows pre-permuted) ----------------
__global__ void k_xw2_mfma(float* ws){
    __shared__ __align__(16) unsigned short Ash[128*128];
    __shared__ __align__(16) unsigned short Bsh[128*128];
    const unsigned short* h1b  = (const unsigned short*)(ws + O_H1B);
    const unsigned short* w2bt = (const unsigned short*)(ws + O_W2BT);
    long bm = (long)blockIdx.x * 128;
    long bn = (long)blockIdx.y * 128;
    int tid = threadIdx.x;
    char* Ac = (char*)Ash; char* Bc = (char*)Bsh;
    #pragma unroll
    for (int i = 0; i < 8; i++){
        int c = tid + i*256;
        int row = c >> 4, kb = (c & 15) * 16;
        int off = row*256 + (kb ^ ((row & 7) << 4));
        *(bf16x8*)(Ac + off) = *(const bf16x8*)&h1b [(bm + row)*128 + (c & 15)*8];
        *(bf16x8*)(Bc + off) = *(const bf16x8*)&w2bt[(bn + row)*128 + (c & 15)*8];
    }
    __syncthreads();
    int w = tid >> 6, lane = tid & 63;
    int wm = (w >> 1) * 64, wn = (w & 1) * 64;
    int r16 = lane & 15, kq = lane >> 4;
    f32x4 acc[4][4] = {};
    #pragma unroll
    for (int ks = 0; ks < 4; ks++){
        int kbyte = ks*64 + kq*16;
        bf16x8 a[4], b[4];
        #pragma unroll
        for (int m = 0; m < 4; m++){
            int row = wm + m*16 + r16;
            a[m] = *(const bf16x8*)(Ac + row*256 + (kbyte ^ ((row & 7) << 4)));
        }
        #pragma unroll
        for (int n = 0; n < 4; n++){
            int row = wn + n*16 + r16;
            b[n] = *(const bf16x8*)(Bc + row*256 + (kbyte ^ ((row & 7) << 4)));
        }
        #pragma unroll
        for (int m = 0; m < 4; m++)
            #pragma unroll
            for (int n = 0; n < 4; n++)
                acc[m][n] = __builtin_amdgcn_mfma_f32_16x16x32_bf16(a[m], b[n], acc[m][n], 0, 0, 0);
    }
    __hip_bfloat16* xb = (__hip_bfloat16*)(ws + O_XW2);
    #pragma unroll
    for (int m = 0; m < 4; m++){
        long gr0 = bm + wm + m*16 + kq*4;
        #pragma unroll
        for (int j = 0; j < 4; j++){
            long gr = gr0 + j;
            if (gr < NN){
                #pragma unroll
                for (int n = 0; n < 4; n++){
                    long gc = bn + wn + n*16 + r16;
                    xb[gr*2048 + gc] = __float2bfloat16(acc[m][n][j]);
                }
            }
        }
    }
}

// ---------------- layer-2: 16 nodes/block, 16 lanes/node, barrier-free ----------------
__global__ __launch_bounds__(256) void k_node2(const int* ei, const int* et, float* ws){
    __shared__ float exs[16][16][4];   // normalized weights a_jh = ex*0.25/den
    __shared__ int   srts[16][16];
    int tid = threadIdx.x;
    int g = tid >> 4, t = tid & 15;
    long n = (long)blockIdx.x*16 + g;
    const int* rowp = (const int*)(ws + O_ROWP);
    const int* perm = (const int*)(ws + O_PERM);
    int e0 = rowp[n], deg = rowp[n+1] - e0;
    bool have = t < deg;
    float al[4]; int srt = 0;
    float mx[4] = {-3.0e38f,-3.0e38f,-3.0e38f,-3.0e38f};
    if (have){
        int e = perm[e0 + t]; int src = ei[e]; int rt = et[e]; srt = src*4 + rt;
        float4 q4 = *(const float4*)&ws[O_AQ + n*16 + rt*4];
        float4 k4 = *(const float4*)&ws[O_AK + (long)src*16 + rt*4];
        al[0] = lrelu_f(q4.x + k4.x); al[1] = lrelu_f(q4.y + k4.y);
        al[2] = lrelu_f(q4.z + k4.z); al[3] = lrelu_f(q4.w + k4.w);
        #pragma unroll
        for (int h = 0; h < 4; h++) mx[h] = al[h];
    }
    for (int j0 = 16; j0 < deg; j0 += 16){   // rare
        int j = j0 + t;
        if (j < deg){
            int e = perm[e0 + j]; int src = ei[e]; int rt = et[e];
            float4 q4 = *(const float4*)&ws[O_AQ + n*16 + rt*4];
            float4 k4 = *(const float4*)&ws[O_AK + (long)src*16 + rt*4];
            mx[0] = fmaxf(mx[0], lrelu_f(q4.x + k4.x));
            mx[1] = fmaxf(mx[1], lrelu_f(q4.y + k4.y));
            mx[2] = fmaxf(mx[2], lrelu_f(q4.z + k4.z));
            mx[3] = fmaxf(mx[3], lrelu_f(q4.w + k4.w));
        }
    }
    #pragma unroll
    for (int h = 0; h < 4; h++) mx[h] = g16_max(mx[h]);
    float den[4] = {0.f,0.f,0.f,0.f};
    float ex[4] = {0.f,0.f,0.f,0.f};
    if (have){
        #pragma unroll
        for (int h = 0; h < 4; h++){ ex[h] = expf(al[h] - mx[h]); den[h] = ex[h]; }
    }
    for (int j0 = 16; j0 < deg; j0 += 16){   // rare
        int j = j0 + t;
        if (j < deg){
            int e = perm[e0 + j]; int src = ei[e]; int rt = et[e];
            float4 q4 = *(const float4*)&ws[O_AQ + n*16 + rt*4];
            float4 k4 = *(const float4*)&ws[O_AK + (long)src*16 + rt*4];
            den[0] += expf(lrelu_f(q4.x + k4.x) - mx[0]);
            den[1] += expf(lrelu_f(q4.y + k4.y) - mx[1]);
            den[2] += expf(lrelu_f(q4.z + k4.z) - mx[2]);
            den[3] += expf(lrelu_f(q4.w + k4.w) - mx[3]);
        }
    }
    #pragma unroll
    for (int h = 0; h < 4; h++) den[h] = g16_sum(den[h]);
    float rd[4];
    #pragma unroll
    for (int h = 0; h < 4; h++) rd[h] = den[h] > 0.f ? 0.25f/den[h] : 0.f;
    if (have){
        exs[g][t][0] = ex[0]*rd[0]; exs[g][t][1] = ex[1]*rd[1];
        exs[g][t][2] = ex[2]*rd[2]; exs[g][t][3] = ex[3]*rd[3];
        srts[g][t] = srt;
    }
    // pass 3 (same-wave LDS read after write: ordered, no barrier)
    const unsigned short* xw2 = (const unsigned short*)(ws + O_XW2);
    float acc[8];
    #pragma unroll
    for (int k = 0; k < 8; k++) acc[k] = 0.f;
    int mdeg = min(deg, 16);
    for (int j = 0; j < mdeg; j++){
        float4 a4 = *(const float4*)exs[g][j];
        long sr = srts[g][j];
        const u16x8* row = (const u16x8*)(xw2 + sr*512 + t*32);
        u16x8 v0 = row[0], v1 = row[1], v2 = row[2], v3 = row[3];
        acc[0] += a4.x*bf2f(v0[0]) + a4.y*bf2f(v0[1]) + a4.z*bf2f(v0[2]) + a4.w*bf2f(v0[3]);
        acc[1] += a4.x*bf2f(v0[4]) + a4.y*bf2f(v0[5]) + a4.z*bf2f(v0[6]) + a4.w*bf2f(v0[7]);
        acc[2] += a4.x*bf2f(v1[0]) + a4.y*bf2f(v1[1]) + a4.z*bf2f(v1[2]) + a4.w*bf2f(v1[3]);
        acc[3] += a4.x*bf2f(v1[4]) + a4.y*bf2f(v1[5]) + a4.z*bf2f(v1[6]) + a4.w*bf2f(v1[7]);
        acc[4] += a4.x*bf2f(v2[0]) + a4.y*bf2f(v2[1]) + a4.z*bf2f(v2[2]) + a4.w*bf2f(v2[3]);
        acc[5] += a4.x*bf2f(v2[4]) + a4.y*bf2f(v2[5]) + a4.z*bf2f(v2[6]) + a4.w*bf2f(v2[7]);
        acc[6] += a4.x*bf2f(v3[0]) + a4.y*bf2f(v3[1]) + a4.z*bf2f(v3[2]) + a4.w*bf2f(v3[3]);
        acc[7] += a4.x*bf2f(v3[4]) + a4.y*bf2f(v3[5]) + a4.z*bf2f(v3[6]) + a4.w*bf2f(v3[7]);
    }
    for (int j = 16; j < deg; j++){          // rare: group-uniform recompute
        int e = perm[e0 + j]; int src = ei[e]; int rt = et[e];
        float4 q4 = *(const float4*)&ws[O_AQ + n*16 + rt*4];
        float4 k4 = *(const float4*)&ws[O_AK + (long)src*16 + rt*4];
        float4 a4;
        a4.x = expf(lrelu_f(q4.x + k4.x) - mx[0])*rd[0];
        a4.y = expf(lrelu_f(q4.y + k4.y) - mx[1])*rd[1];
        a4.z = expf(lrelu_f(q4.z + k4.z) - mx[2])*rd[2];
        a4.w = expf(lrelu_f(q4.w + k4.w) - mx[3])*rd[3];
        const u16x8* row = (const u16x8*)(xw2 + ((long)src*4 + rt)*512 + t*32);
        u16x8 v0 = row[0], v1 = row[1], v2 = row[2], v3 = row[3];
        acc[0] += a4.x*bf2f(v0[0]) + a4.y*bf2f(v0[1]) + a4.z*bf2f(v0[2]) + a4.w*bf2f(v0[3]);
        acc[1] += a4.x*bf2f(v0[4]) + a4.y*bf2f(v0[5]) + a4.z*bf2f(v0[6]) + a4.w*bf2f(v0[7]);
        acc[2] += a4.x*bf2f(v1[0]) + a4.y*bf2f(v1[1]) + a4.z*bf2f(v1[2]) + a4.w*bf2f(v1[3]);
        acc[3] += a4.x*bf2f(v1[4]) + a4.y*bf2f(v1[5]) + a4.z*bf2f(v1[6]) + a4.w*bf2f(v1[7]);
        acc[4] += a4.x*bf2f(v2[0]) + a4.y*bf2f(v2[1]) + a4.z*bf2f(v2[2]) + a4.w*bf2f(v2[3]);
        acc[5] += a4.x*bf2f(v2[4]) + a4.y*bf2f(v2[5]) + a4.z*bf2f(v2[6]) + a4.w*bf2f(v2[7]);
        acc[6] += a4.x*bf2f(v3[0]) + a4.y*bf2f(v3[1]) + a4.z*bf2f(v3[2]) + a4.w*bf2f(v3[3]);
        acc[7] += a4.x*bf2f(v3[4]) + a4.y*bf2f(v3[5]) + a4.z*bf2f(v3[6]) + a4.w*bf2f(v3[7]);
    }
    float4 ba = *(const float4*)&ws[O_B2 + t*8];
    float4 bb = *(const float4*)&ws[O_B2 + t*8 + 4];
    float4 o0, o1;
    o0.x = selu_f(acc[0] + ba.x); o0.y = selu_f(acc[1] + ba.y);
    o0.z = selu_f(acc[2] + ba.z); o0.w = selu_f(acc[3] + ba.w);
    o1.x = selu_f(acc[4] + bb.x); o1.y = selu_f(acc[5] + bb.y);
    o1.z = selu_f(acc[6] + bb.z); o1.w = selu_f(acc[7] + bb.w);
    *(float4*)&ws[O_H2 + n*128 + t*8]     = o0;
    *(float4*)&ws[O_H2 + n*128 + t*8 + 4] = o1;
}

// ---------------- global add pool ----------------
__global__ void k_pool(float* ws){
    int b = blockIdx.x, d = threadIdx.x;
    float s = 0.f;
    for (int j = 0; j < GN; j++) s += ws[O_H2 + ((long)b*GN + j)*128 + d];
    ws[O_G + (long)b*128 + d] = s;
}

// ---------------- fused tail with transposed (coalesced) weights ----------------
__global__ void k_tail(float* ws, void* d_out, const void* taus_raw){
    __shared__ float cs[64];
    __shared__ float row0[128], row1[128];
    __shared__ float red[2][12];
    __shared__ float advs[12];
    int bt = blockIdx.x, t = threadIdx.x;
    int b = bt >> 3;
    int wid = t >> 6;
    if (t < 64){
        float tau = ws[O_TAU + bt];
        cs[t] = cosf(tau * (3.14159265358979323846f * (float)(t + 1)));
    }
    __syncthreads();
    {
        const float* cwt = ws + O_CWT;                // [c][t]
        float s = ws[O_CB + t];
        #pragma unroll 8
        for (int c = 0; c < 64; c++) s += cs[c]*cwt[c*128 + t];
        s = fmaxf(s, 0.f);
        row0[t] = ws[O_G + (long)b*128 + t] * s;
    }
    __syncthreads();
    {
        const float* wt = ws + O_CF1WT;               // [i][t]
        float s = ws[O_CF1B + t];
        #pragma unroll 8
        for (int i = 0; i < 128; i++) s += row0[i]*wt[i*128 + t];
        row1[t] = selu_f(s);
    }
    __syncthreads();
    float r2;
    {
        const float* wt = ws + O_CF2WT;               // [i][t]
        float s = ws[O_CF2B + t];
        #pragma unroll 8
        for (int i = 0; i < 128; i++) s += row1[i]*wt[i*128 + t];
        r2 = selu_f(s);
    }
    // head: all threads compute coalesced partials, wave-reduce
    float part[11];
    #pragma unroll
    for (int a = 0; a < 10; a++) part[a] = r2 * ws[O_CAW + (long)a*128 + t];
    part[10] = r2 * ws[O_CVW + t];
    #pragma unroll
    for (int a = 0; a < 11; a++) part[a] = w64_sum(part[a]);
    if ((t & 63) == 0){
        #pragma unroll
        for (int a = 0; a < 11; a++) red[wid][a] = part[a];
    }
    __syncthreads();
    if (t == 0){
        float m = 0.f;
        #pragma unroll
        for (int a = 0; a < 11; a++) advs[a] = red[0][a] + red[1][a];
        #pragma unroll
        for (int a = 0; a < 10; a++) m += advs[a];
        m *= 0.1f;
        float val = advs[10];
        int bf = ((const int*)ws)[0];
        if (bf){
            __hip_bfloat16* out = (__hip_bfloat16*)d_out;
            for (int a = 0; a < 10; a++) out[(long)bt*10 + a] = __float2bfloat16(val + advs[a] - m);
            ((unsigned short*)d_out)[16000 + bt] = ((const unsigned short*)taus_raw)[bt];
        } else {
            float* out = (float*)d_out;
            for (int a = 0; a < 10; a++) out[(long)bt*10 + a] = val + advs[a] - m;
            out[16000 + bt] = ((const float*)taus_raw)[bt];
        }
    }
}

// ---------------- launch ----------------
extern "C" void kernel_launch(void* const* d_in, const int* in_sizes, int n_in,
                              void* d_out, int out_size, void* d_ws, size_t ws_size,
                              hipStream_t stream){
    (void)in_sizes; (void)n_in; (void)out_size; (void)ws_size;
    float* ws = (float*)d_ws;
    const int* ei = (const int*)d_in[1];
    const int* et = (const int*)d_in[2];

    hipMemsetAsync(ws + O_DEG, 0, (size_t)(2*NN)*4, stream);

    k_pre<<<626, 256, 0, stream>>>((const unsigned short*)d_in[3], ei, ws);
    k_scan<<<1, 256, 0, stream>>>(ws);

    ConvArgs ca;
    static const long conv_o[38] = {
        O_X, -1, -1, O_TAU, O_W1, O_Q1, O_K1, O_B1, O_W2, O_Q2, O_K2, O_B2, O_CW, O_CB,
        O_F1W, O_F1B, O_F1SW, O_F1SB, O_F1EW, O_F1EB,
        O_F2W, O_F2B, O_F2SW, O_F2SB, O_F2EW, O_F2EB,
        O_AW, O_AB, O_ASW, O_ASB, O_AEW, O_AEB,
        O_VW, O_VB, O_VSW, O_VSB, O_VEW, O_VEB };
    static const int conv_n[38] = {
        40000, 0, 0, 1600, 4096, 2048, 2048, 128, 262144, 2048, 2048, 128, 8192, 128,
        16384, 128, 16384, 128, 16384, 128,
        16384, 128, 16384, 128, 16384, 128,
        1280, 10, 1280, 10, 1280, 10,
        128, 1, 128, 1, 128, 1 };
    for (int i = 0; i < 38; i++){ ca.src[i] = d_in[i]; ca.off[i] = conv_o[i]; ca.n[i] = conv_n[i]; }
    k_conv_scatter<<<dim3(625, 39), 256, 0, stream>>>(ca, ei, ws);

    k_prep<<<dim3(1024, 4), 256, 0, stream>>>(ws);

    k_node1<<<1250, 256, 0, stream>>>(ei, et, ws);

    k_xw2_mfma<<<dim3(157, 16), 256, 0, stream>>>(ws);
    k_aqk<<<1250, 256, 0, stream>>>(ws);
    k_node2<<<1250, 256, 0, stream>>>(ei, et, ws);

    k_pool<<<200, 128, 0, stream>>>(ws);
    k_tail<<<1600, 128, 0, stream>>>(ws, d_out, d_in[3]);
}